// Round 5
// baseline (130.711 us; speedup 1.0000x reference)
//
#include <hip/hip_runtime.h>
#include <hip/hip_bf16.h>

using bf16 = __bf16;
using bf16x4 = __attribute__((ext_vector_type(4))) __bf16;
using bf16x8 = __attribute__((ext_vector_type(8))) __bf16;
using f32x4 = __attribute__((ext_vector_type(4))) float;

#define EXP2F(x) __builtin_amdgcn_exp2f(x)

// ---------------- prep: fp32 -> bf16 (x and ctx in one launch; outputs contiguous) ----------------
__global__ __launch_bounds__(256) void cvt_kernel(const float4* __restrict__ a,
                                                  const float4* __restrict__ b,
                                                  bf16x4* __restrict__ out) {
  int g = blockIdx.x * blockDim.x + threadIdx.x;  // 0 .. 2*1048576-1
  float4 v = (g < 1048576) ? a[g] : b[g - 1048576];
  bf16x4 o = {(bf16)v.x, (bf16)v.y, (bf16)v.z, (bf16)v.w};
  out[g] = o;
}

// ---------------- prep: all 4 weights W[k][n] fp32 -> Wt[n][k] bf16, one launch ----------------
__global__ __launch_bounds__(256) void transpose_kernel(const float* __restrict__ w0,
                                                        const float* __restrict__ w1,
                                                        const float* __restrict__ w2,
                                                        const float* __restrict__ w3,
                                                        bf16* __restrict__ wtbase) {
  __shared__ float tile[32][33];
  const int z = blockIdx.z;
  const float* w = (z == 0) ? w0 : (z == 1) ? w1 : (z == 2) ? w2 : w3;
  bf16* wt = wtbase + (size_t)z * 1048576;
  int k0 = blockIdx.y * 32, n0 = blockIdx.x * 32;
  int tx = threadIdx.x, ty = threadIdx.y;
#pragma unroll
  for (int i = 0; i < 4; i++)
    tile[ty + i * 8][tx] = w[(size_t)(k0 + ty + i * 8) * 1024 + n0 + tx];
  __syncthreads();
#pragma unroll
  for (int i = 0; i < 4; i++)
    wt[(size_t)(n0 + ty + i * 8) * 1024 + k0 + tx] = (bf16)tile[tx][ty + i * 8];
}

// ---------------- GEMM core ----------------
// C[m][n] = A[m][k] * Wt[n][k]^T + bias
// mode 0: out bf16, head-split [(b*16+h)*2048 + t][64]
// mode 1: out bf16, V-transposed [((b*16+h)*64 + d)][2048]
// mode 2: out fp32, plain [m][1024]
__device__ __forceinline__ void gemm_body(const bf16* __restrict__ A,
                                          const bf16* __restrict__ Bt,
                                          const float* __restrict__ bias,
                                          void* __restrict__ outp, int mode, int bx, int by) {
  constexpr int K = 1024;
  __shared__ __align__(16) char smem[34816];
  bf16(*As)[40] = (bf16(*)[40])smem;
  bf16(*Bs)[40] = (bf16(*)[40])(smem + 10240);
  bf16(*Cs)[136] = (bf16(*)[136])smem;

  const int tid = threadIdx.x;
  const int lane = tid & 63;
  const int w = tid >> 6;
  const int wr = w >> 1, wc = w & 1;
  const int m0 = by * 128, n0 = bx * 128;
  const int fr = lane & 15, fg = (lane >> 4) * 8;

  f32x4 acc[4][4] = {};

  const int srow = tid >> 2;
  const int kc = (tid & 3) * 8;
  const int arow = m0 + srow, brow = n0 + srow;

  bf16x8 ra0, ra1, rb0, rb1;
  ra0 = *(const bf16x8*)&A[(size_t)arow * K + kc];
  ra1 = *(const bf16x8*)&A[(size_t)(arow + 64) * K + kc];
  rb0 = *(const bf16x8*)&Bt[(size_t)brow * K + kc];
  rb1 = *(const bf16x8*)&Bt[(size_t)(brow + 64) * K + kc];

  for (int k0 = 0; k0 < K; k0 += 32) {
    __syncthreads();
    *(bf16x8*)&As[srow][kc] = ra0;
    *(bf16x8*)&As[srow + 64][kc] = ra1;
    *(bf16x8*)&Bs[srow][kc] = rb0;
    *(bf16x8*)&Bs[srow + 64][kc] = rb1;
    if (k0 + 32 < K) {
      int kn = k0 + 32 + kc;
      ra0 = *(const bf16x8*)&A[(size_t)arow * K + kn];
      ra1 = *(const bf16x8*)&A[(size_t)(arow + 64) * K + kn];
      rb0 = *(const bf16x8*)&Bt[(size_t)brow * K + kn];
      rb1 = *(const bf16x8*)&Bt[(size_t)(brow + 64) * K + kn];
    }
    __syncthreads();
    bf16x8 af[4], bfr[4];
#pragma unroll
    for (int mi = 0; mi < 4; mi++)
      af[mi] = *(const bf16x8*)&As[wr * 64 + mi * 16 + fr][fg];
#pragma unroll
    for (int ni = 0; ni < 4; ni++)
      bfr[ni] = *(const bf16x8*)&Bs[wc * 64 + ni * 16 + fr][fg];
#pragma unroll
    for (int mi = 0; mi < 4; mi++)
#pragma unroll
      for (int ni = 0; ni < 4; ni++)
        acc[mi][ni] =
            __builtin_amdgcn_mfma_f32_16x16x32_bf16(af[mi], bfr[ni], acc[mi][ni], 0, 0, 0);
  }

  float bv[4];
#pragma unroll
  for (int ni = 0; ni < 4; ni++) bv[ni] = bias[n0 + wc * 64 + ni * 16 + fr];
#pragma unroll
  for (int mi = 0; mi < 4; mi++)
#pragma unroll
    for (int ni = 0; ni < 4; ni++)
#pragma unroll
      for (int j = 0; j < 4; j++) acc[mi][ni][j] += bv[ni];

  if (mode == 2) {
    float* O = (float*)outp;
#pragma unroll
    for (int mi = 0; mi < 4; mi++)
#pragma unroll
      for (int ni = 0; ni < 4; ni++)
#pragma unroll
        for (int j = 0; j < 4; j++) {
          int row = m0 + wr * 64 + mi * 16 + (lane >> 4) * 4 + j;
          int col = n0 + wc * 64 + ni * 16 + fr;
          O[(size_t)row * 1024 + col] = acc[mi][ni][j];
        }
    return;
  }

  __syncthreads();
#pragma unroll
  for (int mi = 0; mi < 4; mi++) {
    int r = wr * 64 + mi * 16 + (lane >> 4) * 4;
#pragma unroll
    for (int ni = 0; ni < 4; ni++) {
      int c = wc * 64 + ni * 16 + fr;
#pragma unroll
      for (int j = 0; j < 4; j++) Cs[r + j][c] = (bf16)acc[mi][ni][j];
    }
  }
  __syncthreads();

  bf16* O = (bf16*)outp;
  if (mode == 0) {
    int row = tid >> 1, ch = (tid & 1) * 64;
    int rg = m0 + row;
    int b = rg >> 11, t_ = rg & 2047;
    int c0 = n0 + ch;
    int h = c0 >> 6;
    bf16* dst = O + ((size_t)(b * 16 + h) * 2048 + t_) * 64;
#pragma unroll
    for (int i = 0; i < 8; i++) *(bf16x8*)&dst[i * 8] = *(const bf16x8*)&Cs[row][ch + i * 8];
  } else {  // mode 1: V^T
    int colL = tid >> 1, sh = (tid & 1) * 64;
    int cg = n0 + colL;
    int h = cg >> 6, d = cg & 63;
    int rg = m0 + sh;
    int b = rg >> 11, s_ = rg & 2047;
    bf16* dst = O + ((size_t)((b * 16 + h) * 64 + d)) * 2048 + s_;
#pragma unroll
    for (int i = 0; i < 8; i++) {
      bf16x8 v;
#pragma unroll
      for (int jj = 0; jj < 8; jj++) v[jj] = Cs[sh + i * 8 + jj][colL];
      *(bf16x8*)&dst[i * 8] = v;
    }
  }
}

// merged Q/K/V projection GEMMs, XCD-chunked swizzle.
// grid = 768 linear blocks; xcd = lin&7 owns seq [xcd*96, xcd*96+96):
// seq -> z (which GEMM), by (A panel), bx fastest (weight panel sweep).
__global__ __launch_bounds__(256) void gemm_qkv_kernel(const bf16* __restrict__ xb,
                                                       const bf16* __restrict__ cb,
                                                       const bf16* __restrict__ wtbase,
                                                       const float* __restrict__ bq,
                                                       const float* __restrict__ bk,
                                                       const float* __restrict__ bv,
                                                       bf16* __restrict__ outbase) {
  const int lin = blockIdx.x;
  const int xcd = lin & 7, idx = lin >> 3;
  const int seq = xcd * 96 + idx;
  const int z = seq >> 8;
  const int rem = seq & 255;
  const int by = rem >> 3, bx = rem & 7;
  const bf16* A = (z == 0) ? xb : cb;
  const bf16* Wt = wtbase + (size_t)z * 1048576;
  const float* bias = (z == 0) ? bq : (z == 1) ? bk : bv;
  bf16* out = outbase + (size_t)z * 4194304;
  gemm_body(A, Wt, bias, (void*)out, (z == 2) ? 1 : 0, bx, by);
}

// output projection GEMM (fp32 out), same XCD-chunked swizzle over 256 blocks
__global__ __launch_bounds__(256) void gemm_o_kernel(const bf16* __restrict__ A,
                                                     const bf16* __restrict__ Wt,
                                                     const float* __restrict__ bias,
                                                     float* __restrict__ out) {
  const int lin = blockIdx.x;
  const int xcd = lin & 7, idx = lin >> 3;
  const int seq = xcd * 32 + idx;
  const int by = seq >> 3, bx = seq & 7;
  gemm_body(A, Wt, bias, (void*)out, 2, bx, by);
}

// ---------------- flash attention ----------------
// 128-thread blocks (2 waves), 32 q-rows per block -> 2048 blocks for backfill.
// grid: x = bh (XCD affinity, 32%8==0), y: tile = 63-y (LPT), q0t = tile*32.
__global__ __launch_bounds__(128) void attn_kernel(const bf16* __restrict__ Q,
                                                   const bf16* __restrict__ Kc,
                                                   const bf16* __restrict__ Vt,
                                                   bf16* __restrict__ Y) {
  const int bh = blockIdx.x;
  const int tile = 63 - blockIdx.y;
  const int q0t = tile * 32;
  const int tid = threadIdx.x, lane = tid & 63, w = tid >> 6;
  const int lr = lane & 15, lg = lane >> 4;
  const int q0 = q0t + w * 16;  // lane's q-row = q0 + lr

  __shared__ __align__(16) bf16 Ks[64 * 64];
  __shared__ __align__(16) bf16 Vs[64 * 64];
  __shared__ __align__(16) bf16 Plds[2][16][72];

  const bf16* qb = Q + ((size_t)bh * 2048 + q0 + lr) * 64 + lg * 8;
  const bf16x8 qfB0 = *(const bf16x8*)qb;
  const bf16x8 qfB1 = *(const bf16x8*)(qb + 32);

  const bf16* Kbase = Kc + (size_t)bh * 2048 * 64;
  const bf16* Vbase = Vt + (size_t)bh * 64 * 2048;

  // staging: 128 threads cover 64 rows x 64 elems; thread = 64B of one row
  const int srow = tid >> 1;
  const int scol = (tid & 1) * 32;
  const int r7x = (srow & 7) * 8;
  int dk[4];
#pragma unroll
  for (int i = 0; i < 4; ++i) dk[i] = srow * 64 + ((scol + i * 8) ^ r7x);

  bf16x8 kr[4], vr[4];
  {
    const bf16* kp = Kbase + (size_t)srow * 64 + scol;
    const bf16* vp = Vbase + (size_t)srow * 2048 + scol;
#pragma unroll
    for (int i = 0; i < 4; ++i) {
      kr[i] = *(const bf16x8*)(kp + i * 8);
      vr[i] = *(const bf16x8*)(vp + i * 8);
    }
  }

  f32x4 yacc[4] = {};
  float mrow = -__builtin_inff(), lrow = 0.0f;
  const float SCL = 0.125f * 1.4426950408889634f;
  const int kxor = (lr & 7) * 8;
  const int nchunk = (q0t >> 6) + 1;

  for (int c = 0; c < nchunk; ++c) {
    const int sbase = c * 64;
    __syncthreads();
#pragma unroll
    for (int i = 0; i < 4; ++i) {
      *(bf16x8*)&Ks[dk[i]] = kr[i];
      *(bf16x8*)&Vs[dk[i]] = vr[i];
    }
    __syncthreads();

    {
      const int cn = (c + 1 < nchunk) ? c + 1 : c;
      const int sb = cn * 64;
      const bf16* kp = Kbase + (size_t)(sb + srow) * 64 + scol;
      const bf16* vp = Vbase + (size_t)srow * 2048 + sb + scol;
#pragma unroll
      for (int i = 0; i < 4; ++i) {
        kr[i] = *(const bf16x8*)(kp + i * 8);
        vr[i] = *(const bf16x8*)(vp + i * 8);
      }
    }

    f32x4 st[4];
#pragma unroll
    for (int h = 0; h < 4; ++h) {
      const int rb = (16 * h + lr) * 64;
      const bf16x8 kf0 = *(const bf16x8*)&Ks[rb + ((lg * 8) ^ kxor)];
      const bf16x8 kf1 = *(const bf16x8*)&Ks[rb + ((32 + lg * 8) ^ kxor)];
      f32x4 z = {};
      z = __builtin_amdgcn_mfma_f32_16x16x32_bf16(kf0, qfB0, z, 0, 0, 0);
      z = __builtin_amdgcn_mfma_f32_16x16x32_bf16(kf1, qfB1, z, 0, 0, 0);
      st[h] = z;
    }
#pragma unroll
    for (int h = 0; h < 4; ++h)
#pragma unroll
      for (int j = 0; j < 4; ++j) st[h][j] *= SCL;
    if (c == nchunk - 1) {  // diagonal chunk: causal mask
      const int qg = q0 + lr;
#pragma unroll
      for (int h = 0; h < 4; ++h)
#pragma unroll
        for (int j = 0; j < 4; ++j) {
          int sg = sbase + 16 * h + lg * 4 + j;
          if (sg > qg) st[h][j] = -__builtin_inff();
        }
    }
    float vmax = fmaxf(fmaxf(st[0][0], st[0][1]), fmaxf(st[0][2], st[0][3]));
#pragma unroll
    for (int h = 1; h < 4; ++h)
      vmax = fmaxf(vmax, fmaxf(fmaxf(st[h][0], st[h][1]), fmaxf(st[h][2], st[h][3])));
    vmax = fmaxf(vmax, __shfl_xor(vmax, 16));
    vmax = fmaxf(vmax, __shfl_xor(vmax, 32));

    // defer-max (exact, THR=0)
    if (!__all(vmax <= mrow)) {
      const float mnew = fmaxf(mrow, vmax);
      const float cf = EXP2F(mrow - mnew);
      mrow = mnew;
      lrow *= cf;
      float cfj[4];
#pragma unroll
      for (int j = 0; j < 4; ++j) cfj[j] = __shfl(cf, lg * 4 + j);
#pragma unroll
      for (int nf = 0; nf < 4; ++nf)
#pragma unroll
        for (int j = 0; j < 4; ++j) yacc[nf][j] *= cfj[j];
    }

    float rs = 0.0f;
#pragma unroll
    for (int h = 0; h < 4; ++h) {
      float p0 = EXP2F(st[h][0] - mrow);
      float p1 = EXP2F(st[h][1] - mrow);
      float p2 = EXP2F(st[h][2] - mrow);
      float p3 = EXP2F(st[h][3] - mrow);
      rs += (p0 + p1) + (p2 + p3);
      bf16x4 pk = {(bf16)p0, (bf16)p1, (bf16)p2, (bf16)p3};
      *(bf16x4*)&Plds[w][lr][16 * h + lg * 4] = pk;
    }
    rs += __shfl_xor(rs, 16);
    rs += __shfl_xor(rs, 32);
    lrow += rs;

    const bf16x8 pa0 = *(const bf16x8*)&Plds[w][lr][lg * 8];
    const bf16x8 pa1 = *(const bf16x8*)&Plds[w][lr][32 + lg * 8];
#pragma unroll
    for (int nf = 0; nf < 4; ++nf) {
      const int rb = (nf * 16 + lr) * 64;
      const bf16x8 vf0 = *(const bf16x8*)&Vs[rb + ((lg * 8) ^ kxor)];
      const bf16x8 vf1 = *(const bf16x8*)&Vs[rb + ((32 + lg * 8) ^ kxor)];
      yacc[nf] = __builtin_amdgcn_mfma_f32_16x16x32_bf16(pa0, vf0, yacc[nf], 0, 0, 0);
      yacc[nf] = __builtin_amdgcn_mfma_f32_16x16x32_bf16(pa1, vf1, yacc[nf], 0, 0, 0);
    }
  }

  const float rinv = 1.0f / lrow;
  float linv[4];
#pragma unroll
  for (int j = 0; j < 4; ++j) linv[j] = __shfl(rinv, lg * 4 + j);
  const int b = bh >> 4, h = bh & 15;
#pragma unroll
  for (int nf = 0; nf < 4; ++nf)
#pragma unroll
    for (int j = 0; j < 4; ++j) {
      int qg = q0 + lg * 4 + j;
      Y[((size_t)b * 2048 + qg) * 1024 + h * 64 + nf * 16 + lr] = (bf16)(yacc[nf][j] * linv[j]);
    }
}

extern "C" void kernel_launch(void* const* d_in, const int* in_sizes, int n_in,
                              void* d_out, int out_size, void* d_ws, size_t ws_size,
                              hipStream_t stream) {
  const float* x = (const float*)d_in[0];
  const float* ctx = (const float*)d_in[1];
  const float* q_w = (const float*)d_in[2];
  const float* q_b = (const float*)d_in[3];
  const float* k_w = (const float*)d_in[4];
  const float* k_b = (const float*)d_in[5];
  const float* v_w = (const float*)d_in[6];
  const float* v_b = (const float*)d_in[7];
  const float* o_w = (const float*)d_in[8];
  const float* o_b = (const float*)d_in[9];

  char* ws = (char*)d_ws;
  const size_t MB = 1024 * 1024;
  bf16* xb = (bf16*)(ws + 0);           // [4096][1024] bf16 (x then ctx contiguous)
  bf16* qwt = (bf16*)(ws + 16 * MB);    // 4 transposed weights, 2MB stride
  bf16* Qws = (bf16*)(ws + 24 * MB);    // Q, K, V^T at 8MB stride
  bf16* Kws = (bf16*)(ws + 32 * MB);
  bf16* Vt = (bf16*)(ws + 40 * MB);
  bf16* Yws = (bf16*)(ws + 48 * MB);
  bf16* owt = qwt + 3 * 1048576;
  bf16* cb = xb + 4194304;

  cvt_kernel<<<8192, 256, 0, stream>>>((const float4*)x, (const float4*)ctx, (bf16x4*)xb);

  dim3 tb(32, 8), tg(32, 32, 4);
  transpose_kernel<<<tg, tb, 0, stream>>>(q_w, k_w, v_w, o_w, qwt);

  gemm_qkv_kernel<<<768, 256, 0, stream>>>(xb, cb, qwt, q_b, k_b, v_b, Qws);

  attn_kernel<<<dim3(32, 64), 128, 0, stream>>>(Qws, Kws, Vt, Yws);

  gemm_o_kernel<<<256, 256, 0, stream>>>(Yws, owt, o_b, (float*)d_out);
}

// Round 6
// 129.666 us; speedup vs baseline: 1.0081x; 1.0081x over previous
//
#include <hip/hip_runtime.h>
#include <hip/hip_bf16.h>

using bf16 = __bf16;
using bf16x4 = __attribute__((ext_vector_type(4))) __bf16;
using bf16x8 = __attribute__((ext_vector_type(8))) __bf16;
using f32x4 = __attribute__((ext_vector_type(4))) float;

#define EXP2F(x) __builtin_amdgcn_exp2f(x)

// ---------------- prep: all 4 weights W[k][n] fp32 -> Wt[n][k] bf16, one launch ----------------
__global__ __launch_bounds__(256) void transpose_kernel(const float* __restrict__ w0,
                                                        const float* __restrict__ w1,
                                                        const float* __restrict__ w2,
                                                        const float* __restrict__ w3,
                                                        bf16* __restrict__ wtbase) {
  __shared__ float tile[32][33];
  const int z = blockIdx.z;
  const float* w = (z == 0) ? w0 : (z == 1) ? w1 : (z == 2) ? w2 : w3;
  bf16* wt = wtbase + (size_t)z * 1048576;
  int k0 = blockIdx.y * 32, n0 = blockIdx.x * 32;
  int tx = threadIdx.x, ty = threadIdx.y;
#pragma unroll
  for (int i = 0; i < 4; i++)
    tile[ty + i * 8][tx] = w[(size_t)(k0 + ty + i * 8) * 1024 + n0 + tx];
  __syncthreads();
#pragma unroll
  for (int i = 0; i < 4; i++)
    wt[(size_t)(n0 + ty + i * 8) * 1024 + k0 + tx] = (bf16)tile[tx][ty + i * 8];
}

// ---------------- GEMM core ----------------
// C[m][n] = (A[m][k] * Wt[n][k]^T + bias) * oscale
// AF32: A is fp32 (converted to bf16 during staging); else A is bf16.
// mode 0: out bf16, head-split [(b*16+h)*2048 + t][64]
// mode 1: out bf16, V-transposed [((b*16+h)*64 + d)][2048]
// mode 2: out fp32, plain [m][1024]
template <int MODE, bool AF32>
__device__ __forceinline__ void gemm_body(const void* __restrict__ Ap,
                                          const bf16* __restrict__ Bt,
                                          const float* __restrict__ bias,
                                          void* __restrict__ outp, int bx, int by,
                                          float oscale) {
  constexpr int K = 1024;
  __shared__ __align__(16) char smem[34816];
  bf16(*As)[40] = (bf16(*)[40])smem;
  bf16(*Bs)[40] = (bf16(*)[40])(smem + 10240);
  bf16(*Cs)[136] = (bf16(*)[136])smem;

  const int tid = threadIdx.x;
  const int lane = tid & 63;
  const int w = tid >> 6;
  const int wr = w >> 1, wc = w & 1;
  const int m0 = by * 128, n0 = bx * 128;
  const int fr = lane & 15, fg = (lane >> 4) * 8;

  f32x4 acc[4][4] = {};

  const int srow = tid >> 2;
  const int kc = (tid & 3) * 8;
  const int arow = m0 + srow, brow = n0 + srow;

  auto loadA = [&](int row, int kcol) -> bf16x8 {
    if constexpr (AF32) {
      const float* Af = (const float*)Ap;
      float4 u = *(const float4*)&Af[(size_t)row * K + kcol];
      float4 v = *(const float4*)&Af[(size_t)row * K + kcol + 4];
      bf16x8 r = {(bf16)u.x, (bf16)u.y, (bf16)u.z, (bf16)u.w,
                  (bf16)v.x, (bf16)v.y, (bf16)v.z, (bf16)v.w};
      return r;
    } else {
      const bf16* Ab = (const bf16*)Ap;
      return *(const bf16x8*)&Ab[(size_t)row * K + kcol];
    }
  };

  bf16x8 ra0, ra1, rb0, rb1;
  ra0 = loadA(arow, kc);
  ra1 = loadA(arow + 64, kc);
  rb0 = *(const bf16x8*)&Bt[(size_t)brow * K + kc];
  rb1 = *(const bf16x8*)&Bt[(size_t)(brow + 64) * K + kc];

  for (int k0 = 0; k0 < K; k0 += 32) {
    __syncthreads();
    *(bf16x8*)&As[srow][kc] = ra0;
    *(bf16x8*)&As[srow + 64][kc] = ra1;
    *(bf16x8*)&Bs[srow][kc] = rb0;
    *(bf16x8*)&Bs[srow + 64][kc] = rb1;
    if (k0 + 32 < K) {
      int kn = k0 + 32 + kc;
      ra0 = loadA(arow, kn);
      ra1 = loadA(arow + 64, kn);
      rb0 = *(const bf16x8*)&Bt[(size_t)brow * K + kn];
      rb1 = *(const bf16x8*)&Bt[(size_t)(brow + 64) * K + kn];
    }
    __syncthreads();
    bf16x8 af[4], bfr[4];
#pragma unroll
    for (int mi = 0; mi < 4; mi++)
      af[mi] = *(const bf16x8*)&As[wr * 64 + mi * 16 + fr][fg];
#pragma unroll
    for (int ni = 0; ni < 4; ni++)
      bfr[ni] = *(const bf16x8*)&Bs[wc * 64 + ni * 16 + fr][fg];
#pragma unroll
    for (int mi = 0; mi < 4; mi++)
#pragma unroll
      for (int ni = 0; ni < 4; ni++)
        acc[mi][ni] =
            __builtin_amdgcn_mfma_f32_16x16x32_bf16(af[mi], bfr[ni], acc[mi][ni], 0, 0, 0);
  }

  float bv[4];
#pragma unroll
  for (int ni = 0; ni < 4; ni++) bv[ni] = bias[n0 + wc * 64 + ni * 16 + fr];
#pragma unroll
  for (int mi = 0; mi < 4; mi++)
#pragma unroll
    for (int ni = 0; ni < 4; ni++)
#pragma unroll
      for (int j = 0; j < 4; j++) acc[mi][ni][j] = (acc[mi][ni][j] + bv[ni]) * oscale;

  if (MODE == 2) {
    float* O = (float*)outp;
#pragma unroll
    for (int mi = 0; mi < 4; mi++)
#pragma unroll
      for (int ni = 0; ni < 4; ni++)
#pragma unroll
        for (int j = 0; j < 4; j++) {
          int row = m0 + wr * 64 + mi * 16 + (lane >> 4) * 4 + j;
          int col = n0 + wc * 64 + ni * 16 + fr;
          O[(size_t)row * 1024 + col] = acc[mi][ni][j];
        }
    return;
  }

  __syncthreads();
#pragma unroll
  for (int mi = 0; mi < 4; mi++) {
    int r = wr * 64 + mi * 16 + (lane >> 4) * 4;
#pragma unroll
    for (int ni = 0; ni < 4; ni++) {
      int c = wc * 64 + ni * 16 + fr;
#pragma unroll
      for (int j = 0; j < 4; j++) Cs[r + j][c] = (bf16)acc[mi][ni][j];
    }
  }
  __syncthreads();

  bf16* O = (bf16*)outp;
  if (MODE == 0) {
    int row = tid >> 1, ch = (tid & 1) * 64;
    int rg = m0 + row;
    int b = rg >> 11, t_ = rg & 2047;
    int c0 = n0 + ch;
    int h = c0 >> 6;
    bf16* dst = O + ((size_t)(b * 16 + h) * 2048 + t_) * 64;
#pragma unroll
    for (int i = 0; i < 8; i++) *(bf16x8*)&dst[i * 8] = *(const bf16x8*)&Cs[row][ch + i * 8];
  } else {  // mode 1: V^T
    int colL = tid >> 1, sh = (tid & 1) * 64;
    int cg = n0 + colL;
    int h = cg >> 6, d = cg & 63;
    int rg = m0 + sh;
    int b = rg >> 11, s_ = rg & 2047;
    bf16* dst = O + ((size_t)((b * 16 + h) * 64 + d)) * 2048 + s_;
#pragma unroll
    for (int i = 0; i < 8; i++) {
      bf16x8 v;
#pragma unroll
      for (int jj = 0; jj < 8; jj++) v[jj] = Cs[sh + i * 8 + jj][colL];
      *(bf16x8*)&dst[i * 8] = v;
    }
  }
}

// merged Q/K/V projection GEMMs, XCD-chunked swizzle; A read directly from fp32 x/ctx.
// Q output pre-scaled by 1/sqrt(64)*log2(e) (folded attention scale).
__global__ __launch_bounds__(256) void gemm_qkv_kernel(const float* __restrict__ x,
                                                       const float* __restrict__ ctx,
                                                       const bf16* __restrict__ wtbase,
                                                       const float* __restrict__ bq,
                                                       const float* __restrict__ bk,
                                                       const float* __restrict__ bv,
                                                       bf16* __restrict__ outbase) {
  const int lin = blockIdx.x;
  const int xcd = lin & 7, idx = lin >> 3;
  const int seq = xcd * 96 + idx;
  const int z = seq >> 8;
  const int rem = seq & 255;
  const int by = rem >> 3, bx = rem & 7;
  const float* A = (z == 0) ? x : ctx;
  const bf16* Wt = wtbase + (size_t)z * 1048576;
  const float* bias = (z == 0) ? bq : (z == 1) ? bk : bv;
  bf16* out = outbase + (size_t)z * 4194304;
  const float oscale = (z == 0) ? 0.125f * 1.4426950408889634f : 1.0f;
  if (z == 2)
    gemm_body<1, true>(A, Wt, bias, (void*)out, bx, by, oscale);
  else
    gemm_body<0, true>(A, Wt, bias, (void*)out, bx, by, oscale);
}

// output projection GEMM (fp32 out), XCD-chunked swizzle over 256 blocks
__global__ __launch_bounds__(256) void gemm_o_kernel(const bf16* __restrict__ A,
                                                     const bf16* __restrict__ Wt,
                                                     const float* __restrict__ bias,
                                                     float* __restrict__ out) {
  const int lin = blockIdx.x;
  const int xcd = lin & 7, idx = lin >> 3;
  const int seq = xcd * 32 + idx;
  const int by = seq >> 3, bx = seq & 7;
  gemm_body<2, false>(A, Wt, bias, (void*)out, bx, by, 1.0f);
}

// ---------------- flash attention (r4 structure: 256 threads, 64 q-rows, defer-max) ----------------
// Q pre-scaled. grid: x = bh (XCD affinity), y: qt = 31-y (LPT).
__global__ __launch_bounds__(256) void attn_kernel(const bf16* __restrict__ Q,
                                                   const bf16* __restrict__ Kc,
                                                   const bf16* __restrict__ Vt,
                                                   bf16* __restrict__ Y) {
  const int bh = blockIdx.x;
  const int qt = 31 - blockIdx.y;
  const int tid = threadIdx.x, lane = tid & 63, w = tid >> 6;
  const int lr = lane & 15, lg = lane >> 4;
  const int q0 = qt * 64 + w * 16;  // lane's q-row = q0 + lr

  __shared__ __align__(16) bf16 Ks[64 * 64];
  __shared__ __align__(16) bf16 Vs[64 * 64];
  __shared__ __align__(16) bf16 Plds[4][16][72];

  const bf16* qb = Q + ((size_t)bh * 2048 + q0 + lr) * 64 + lg * 8;
  const bf16x8 qfB0 = *(const bf16x8*)qb;
  const bf16x8 qfB1 = *(const bf16x8*)(qb + 32);

  const bf16* Kbase = Kc + (size_t)bh * 2048 * 64;
  const bf16* Vbase = Vt + (size_t)bh * 64 * 2048;

  const int srow = tid >> 2;
  const int scol = (tid & 3) * 16;
  const int r7x = (srow & 7) * 8;
  const int d0 = srow * 64 + (scol ^ r7x);
  const int d1 = srow * 64 + ((scol + 8) ^ r7x);

  bf16x8 kr0, kr1, vr0, vr1;
  {
    const bf16* kp = Kbase + (size_t)srow * 64 + scol;
    kr0 = *(const bf16x8*)kp;
    kr1 = *(const bf16x8*)(kp + 8);
    const bf16* vp = Vbase + (size_t)srow * 2048 + scol;
    vr0 = *(const bf16x8*)vp;
    vr1 = *(const bf16x8*)(vp + 8);
  }

  f32x4 yacc[4] = {};
  float mrow = -__builtin_inff(), lrow = 0.0f;
  const int kxor = (lr & 7) * 8;

  for (int c = 0; c <= qt; ++c) {
    const int sbase = c * 64;
    __syncthreads();
    *(bf16x8*)&Ks[d0] = kr0;
    *(bf16x8*)&Ks[d1] = kr1;
    *(bf16x8*)&Vs[d0] = vr0;
    *(bf16x8*)&Vs[d1] = vr1;
    __syncthreads();

    {
      const int cn = (c < qt) ? c + 1 : c;
      const int sb = cn * 64;
      const bf16* kp = Kbase + (size_t)(sb + srow) * 64 + scol;
      kr0 = *(const bf16x8*)kp;
      kr1 = *(const bf16x8*)(kp + 8);
      const bf16* vp = Vbase + (size_t)srow * 2048 + sb + scol;
      vr0 = *(const bf16x8*)vp;
      vr1 = *(const bf16x8*)(vp + 8);
    }

    f32x4 st[4];
#pragma unroll
    for (int h = 0; h < 4; ++h) {
      const int rb = (16 * h + lr) * 64;
      const bf16x8 kf0 = *(const bf16x8*)&Ks[rb + ((lg * 8) ^ kxor)];
      const bf16x8 kf1 = *(const bf16x8*)&Ks[rb + ((32 + lg * 8) ^ kxor)];
      f32x4 z = {};
      z = __builtin_amdgcn_mfma_f32_16x16x32_bf16(kf0, qfB0, z, 0, 0, 0);
      z = __builtin_amdgcn_mfma_f32_16x16x32_bf16(kf1, qfB1, z, 0, 0, 0);
      st[h] = z;
    }
    if (c == qt) {  // diagonal chunk: causal mask (Q already pre-scaled)
      const int qg = q0 + lr;
#pragma unroll
      for (int h = 0; h < 4; ++h)
#pragma unroll
        for (int j = 0; j < 4; ++j) {
          int sg = sbase + 16 * h + lg * 4 + j;
          if (sg > qg) st[h][j] = -__builtin_inff();
        }
    }
    float vmax = fmaxf(fmaxf(st[0][0], st[0][1]), fmaxf(st[0][2], st[0][3]));
#pragma unroll
    for (int h = 1; h < 4; ++h)
      vmax = fmaxf(vmax, fmaxf(fmaxf(st[h][0], st[h][1]), fmaxf(st[h][2], st[h][3])));
    vmax = fmaxf(vmax, __shfl_xor(vmax, 16));
    vmax = fmaxf(vmax, __shfl_xor(vmax, 32));

    // defer-max (exact, THR=0)
    if (!__all(vmax <= mrow)) {
      const float mnew = fmaxf(mrow, vmax);
      const float cf = EXP2F(mrow - mnew);
      mrow = mnew;
      lrow *= cf;
      float cfj[4];
#pragma unroll
      for (int j = 0; j < 4; ++j) cfj[j] = __shfl(cf, lg * 4 + j);
#pragma unroll
      for (int nf = 0; nf < 4; ++nf)
#pragma unroll
        for (int j = 0; j < 4; ++j) yacc[nf][j] *= cfj[j];
    }

    float rs = 0.0f;
#pragma unroll
    for (int h = 0; h < 4; ++h) {
      float p0 = EXP2F(st[h][0] - mrow);
      float p1 = EXP2F(st[h][1] - mrow);
      float p2 = EXP2F(st[h][2] - mrow);
      float p3 = EXP2F(st[h][3] - mrow);
      rs += (p0 + p1) + (p2 + p3);
      bf16x4 pk = {(bf16)p0, (bf16)p1, (bf16)p2, (bf16)p3};
      *(bf16x4*)&Plds[w][lr][16 * h + lg * 4] = pk;
    }
    rs += __shfl_xor(rs, 16);
    rs += __shfl_xor(rs, 32);
    lrow += rs;

    const bf16x8 pa0 = *(const bf16x8*)&Plds[w][lr][lg * 8];
    const bf16x8 pa1 = *(const bf16x8*)&Plds[w][lr][32 + lg * 8];
#pragma unroll
    for (int nf = 0; nf < 4; ++nf) {
      const int rb = (nf * 16 + lr) * 64;
      const bf16x8 vf0 = *(const bf16x8*)&Vs[rb + ((lg * 8) ^ kxor)];
      const bf16x8 vf1 = *(const bf16x8*)&Vs[rb + ((32 + lg * 8) ^ kxor)];
      yacc[nf] = __builtin_amdgcn_mfma_f32_16x16x32_bf16(pa0, vf0, yacc[nf], 0, 0, 0);
      yacc[nf] = __builtin_amdgcn_mfma_f32_16x16x32_bf16(pa1, vf1, yacc[nf], 0, 0, 0);
    }
  }

  const float rinv = 1.0f / lrow;
  float linv[4];
#pragma unroll
  for (int j = 0; j < 4; ++j) linv[j] = __shfl(rinv, lg * 4 + j);
  const int b = bh >> 4, h = bh & 15;
#pragma unroll
  for (int nf = 0; nf < 4; ++nf)
#pragma unroll
    for (int j = 0; j < 4; ++j) {
      int qg = q0 + lg * 4 + j;
      Y[((size_t)b * 2048 + qg) * 1024 + h * 64 + nf * 16 + lr] = (bf16)(yacc[nf][j] * linv[j]);
    }
}

extern "C" void kernel_launch(void* const* d_in, const int* in_sizes, int n_in,
                              void* d_out, int out_size, void* d_ws, size_t ws_size,
                              hipStream_t stream) {
  const float* x = (const float*)d_in[0];
  const float* ctx = (const float*)d_in[1];
  const float* q_w = (const float*)d_in[2];
  const float* q_b = (const float*)d_in[3];
  const float* k_w = (const float*)d_in[4];
  const float* k_b = (const float*)d_in[5];
  const float* v_w = (const float*)d_in[6];
  const float* v_b = (const float*)d_in[7];
  const float* o_w = (const float*)d_in[8];
  const float* o_b = (const float*)d_in[9];

  char* ws = (char*)d_ws;
  const size_t MB = 1024 * 1024;
  bf16* qwt = (bf16*)(ws + 0);         // 4 transposed weights, 2MB stride
  bf16* Qws = (bf16*)(ws + 8 * MB);    // Q, K, V^T at 8MB stride
  bf16* Kws = (bf16*)(ws + 16 * MB);
  bf16* Vt = (bf16*)(ws + 24 * MB);
  bf16* Yws = (bf16*)(ws + 32 * MB);
  bf16* owt = qwt + 3 * 1048576;

  dim3 tb(32, 8), tg(32, 32, 4);
  transpose_kernel<<<tg, tb, 0, stream>>>(q_w, k_w, v_w, o_w, qwt);

  gemm_qkv_kernel<<<768, 256, 0, stream>>>(x, ctx, qwt, q_b, k_b, v_b, Qws);

  attn_kernel<<<dim3(32, 32), 256, 0, stream>>>(Qws, Kws, Vt, Yws);

  gemm_o_kernel<<<256, 256, 0, stream>>>(Yws, owt, o_b, (float*)d_out);
}

// Round 7
// 115.084 us; speedup vs baseline: 1.1358x; 1.1267x over previous
//
#include <hip/hip_runtime.h>
#include <hip/hip_bf16.h>

using bf16 = __bf16;
using bf16x4 = __attribute__((ext_vector_type(4))) __bf16;
using bf16x8 = __attribute__((ext_vector_type(8))) __bf16;
using f32x4 = __attribute__((ext_vector_type(4))) float;

#define EXP2F(x) __builtin_amdgcn_exp2f(x)

// ---------------- prep: all 4 weights W[k][n] fp32 -> Wt[n][k] bf16, one launch ----------------
__global__ __launch_bounds__(256) void transpose_kernel(const float* __restrict__ w0,
                                                        const float* __restrict__ w1,
                                                        const float* __restrict__ w2,
                                                        const float* __restrict__ w3,
                                                        bf16* __restrict__ wtbase) {
  __shared__ float tile[32][33];
  const int z = blockIdx.z;
  const float* w = (z == 0) ? w0 : (z == 1) ? w1 : (z == 2) ? w2 : w3;
  bf16* wt = wtbase + (size_t)z * 1048576;
  int k0 = blockIdx.y * 32, n0 = blockIdx.x * 32;
  int tx = threadIdx.x, ty = threadIdx.y;
#pragma unroll
  for (int i = 0; i < 4; i++)
    tile[ty + i * 8][tx] = w[(size_t)(k0 + ty + i * 8) * 1024 + n0 + tx];
  __syncthreads();
#pragma unroll
  for (int i = 0; i < 4; i++)
    wt[(size_t)(n0 + ty + i * 8) * 1024 + k0 + tx] = (bf16)tile[tx][ty + i * 8];
}

// ---------------- GEMM core (LDS passed in: ONE allocation per kernel) ----------------
// C[m][n] = (A[m][k] * Wt[n][k]^T + bias) * oscale
// AF32: A is fp32 (converted to bf16 during staging); else A is bf16.
// MODE 0: out bf16, head-split [(b*16+h)*2048 + t][64]
// MODE 1: out bf16, V-transposed [((b*16+h)*64 + d)][2048]
// MODE 2: out fp32, plain [m][1024]
template <int MODE, bool AF32>
__device__ __forceinline__ void gemm_body(char* __restrict__ smem,
                                          const void* __restrict__ Ap,
                                          const bf16* __restrict__ Bt,
                                          const float* __restrict__ bias,
                                          void* __restrict__ outp, int bx, int by,
                                          float oscale) {
  constexpr int K = 1024;
  bf16(*As)[40] = (bf16(*)[40])smem;
  bf16(*Bs)[40] = (bf16(*)[40])(smem + 10240);
  bf16(*Cs)[136] = (bf16(*)[136])smem;

  const int tid = threadIdx.x;
  const int lane = tid & 63;
  const int w = tid >> 6;
  const int wr = w >> 1, wc = w & 1;
  const int m0 = by * 128, n0 = bx * 128;
  const int fr = lane & 15, fg = (lane >> 4) * 8;

  f32x4 acc[4][4] = {};

  const int srow = tid >> 2;
  const int kc = (tid & 3) * 8;
  const int arow = m0 + srow, brow = n0 + srow;

  auto loadA = [&](int row, int kcol) -> bf16x8 {
    if constexpr (AF32) {
      const float* Af = (const float*)Ap;
      float4 u = *(const float4*)&Af[(size_t)row * K + kcol];
      float4 v = *(const float4*)&Af[(size_t)row * K + kcol + 4];
      bf16x8 r = {(bf16)u.x, (bf16)u.y, (bf16)u.z, (bf16)u.w,
                  (bf16)v.x, (bf16)v.y, (bf16)v.z, (bf16)v.w};
      return r;
    } else {
      const bf16* Ab = (const bf16*)Ap;
      return *(const bf16x8*)&Ab[(size_t)row * K + kcol];
    }
  };

  bf16x8 ra0, ra1, rb0, rb1;
  ra0 = loadA(arow, kc);
  ra1 = loadA(arow + 64, kc);
  rb0 = *(const bf16x8*)&Bt[(size_t)brow * K + kc];
  rb1 = *(const bf16x8*)&Bt[(size_t)(brow + 64) * K + kc];

  for (int k0 = 0; k0 < K; k0 += 32) {
    __syncthreads();
    *(bf16x8*)&As[srow][kc] = ra0;
    *(bf16x8*)&As[srow + 64][kc] = ra1;
    *(bf16x8*)&Bs[srow][kc] = rb0;
    *(bf16x8*)&Bs[srow + 64][kc] = rb1;
    if (k0 + 32 < K) {
      int kn = k0 + 32 + kc;
      ra0 = loadA(arow, kn);
      ra1 = loadA(arow + 64, kn);
      rb0 = *(const bf16x8*)&Bt[(size_t)brow * K + kn];
      rb1 = *(const bf16x8*)&Bt[(size_t)(brow + 64) * K + kn];
    }
    __syncthreads();
    bf16x8 af[4], bfr[4];
#pragma unroll
    for (int mi = 0; mi < 4; mi++)
      af[mi] = *(const bf16x8*)&As[wr * 64 + mi * 16 + fr][fg];
#pragma unroll
    for (int ni = 0; ni < 4; ni++)
      bfr[ni] = *(const bf16x8*)&Bs[wc * 64 + ni * 16 + fr][fg];
#pragma unroll
    for (int mi = 0; mi < 4; mi++)
#pragma unroll
      for (int ni = 0; ni < 4; ni++)
        acc[mi][ni] =
            __builtin_amdgcn_mfma_f32_16x16x32_bf16(af[mi], bfr[ni], acc[mi][ni], 0, 0, 0);
  }

  float bv[4];
#pragma unroll
  for (int ni = 0; ni < 4; ni++) bv[ni] = bias[n0 + wc * 64 + ni * 16 + fr];
#pragma unroll
  for (int mi = 0; mi < 4; mi++)
#pragma unroll
    for (int ni = 0; ni < 4; ni++)
#pragma unroll
      for (int j = 0; j < 4; j++) acc[mi][ni][j] = (acc[mi][ni][j] + bv[ni]) * oscale;

  if (MODE == 2) {
    float* O = (float*)outp;
#pragma unroll
    for (int mi = 0; mi < 4; mi++)
#pragma unroll
      for (int ni = 0; ni < 4; ni++)
#pragma unroll
        for (int j = 0; j < 4; j++) {
          int row = m0 + wr * 64 + mi * 16 + (lane >> 4) * 4 + j;
          int col = n0 + wc * 64 + ni * 16 + fr;
          O[(size_t)row * 1024 + col] = acc[mi][ni][j];
        }
    return;
  }

  __syncthreads();
#pragma unroll
  for (int mi = 0; mi < 4; mi++) {
    int r = wr * 64 + mi * 16 + (lane >> 4) * 4;
#pragma unroll
    for (int ni = 0; ni < 4; ni++) {
      int c = wc * 64 + ni * 16 + fr;
#pragma unroll
      for (int j = 0; j < 4; j++) Cs[r + j][c] = (bf16)acc[mi][ni][j];
    }
  }
  __syncthreads();

  bf16* O = (bf16*)outp;
  if (MODE == 0) {
    int row = tid >> 1, ch = (tid & 1) * 64;
    int rg = m0 + row;
    int b = rg >> 11, t_ = rg & 2047;
    int c0 = n0 + ch;
    int h = c0 >> 6;
    bf16* dst = O + ((size_t)(b * 16 + h) * 2048 + t_) * 64;
#pragma unroll
    for (int i = 0; i < 8; i++) *(bf16x8*)&dst[i * 8] = *(const bf16x8*)&Cs[row][ch + i * 8];
  } else {  // MODE 1: V^T
    int colL = tid >> 1, sh = (tid & 1) * 64;
    int cg = n0 + colL;
    int h = cg >> 6, d = cg & 63;
    int rg = m0 + sh;
    int b = rg >> 11, s_ = rg & 2047;
    bf16* dst = O + ((size_t)((b * 16 + h) * 64 + d)) * 2048 + s_;
#pragma unroll
    for (int i = 0; i < 8; i++) {
      bf16x8 v;
#pragma unroll
      for (int jj = 0; jj < 8; jj++) v[jj] = Cs[sh + i * 8 + jj][colL];
      *(bf16x8*)&dst[i * 8] = v;
    }
  }
}

// merged Q/K/V projection GEMMs, XCD-chunked swizzle; A read directly from fp32 x/ctx.
// Q output pre-scaled by 1/sqrt(64)*log2(e) (folded attention scale).
__global__ __launch_bounds__(256) void gemm_qkv_kernel(const float* __restrict__ x,
                                                       const float* __restrict__ ctx,
                                                       const bf16* __restrict__ wtbase,
                                                       const float* __restrict__ bq,
                                                       const float* __restrict__ bk,
                                                       const float* __restrict__ bv,
                                                       bf16* __restrict__ outbase) {
  __shared__ __align__(16) char smem[34816];  // ONE allocation shared by both instantiations
  const int lin = blockIdx.x;
  const int xcd = lin & 7, idx = lin >> 3;
  const int seq = xcd * 96 + idx;
  const int z = seq >> 8;
  const int rem = seq & 255;
  const int by = rem >> 3, bx = rem & 7;
  const float* A = (z == 0) ? x : ctx;
  const bf16* Wt = wtbase + (size_t)z * 1048576;
  const float* bias = (z == 0) ? bq : (z == 1) ? bk : bv;
  bf16* out = outbase + (size_t)z * 4194304;
  const float oscale = (z == 0) ? 0.125f * 1.4426950408889634f : 1.0f;
  if (z == 2)
    gemm_body<1, true>(smem, A, Wt, bias, (void*)out, bx, by, oscale);
  else
    gemm_body<0, true>(smem, A, Wt, bias, (void*)out, bx, by, oscale);
}

// output projection GEMM (fp32 out), XCD-chunked swizzle over 256 blocks
__global__ __launch_bounds__(256) void gemm_o_kernel(const bf16* __restrict__ A,
                                                     const bf16* __restrict__ Wt,
                                                     const float* __restrict__ bias,
                                                     float* __restrict__ out) {
  __shared__ __align__(16) char smem[34816];
  const int lin = blockIdx.x;
  const int xcd = lin & 7, idx = lin >> 3;
  const int seq = xcd * 32 + idx;
  const int by = seq >> 3, bx = seq & 7;
  gemm_body<2, false>(smem, A, Wt, bias, (void*)out, bx, by, 1.0f);
}

// ---------------- flash attention (256 threads, 64 q-rows, defer-max, Q pre-scaled) ----------------
__global__ __launch_bounds__(256) void attn_kernel(const bf16* __restrict__ Q,
                                                   const bf16* __restrict__ Kc,
                                                   const bf16* __restrict__ Vt,
                                                   bf16* __restrict__ Y) {
  const int bh = blockIdx.x;
  const int qt = 31 - blockIdx.y;
  const int tid = threadIdx.x, lane = tid & 63, w = tid >> 6;
  const int lr = lane & 15, lg = lane >> 4;
  const int q0 = qt * 64 + w * 16;  // lane's q-row = q0 + lr

  __shared__ __align__(16) bf16 Ks[64 * 64];
  __shared__ __align__(16) bf16 Vs[64 * 64];
  __shared__ __align__(16) bf16 Plds[4][16][72];

  const bf16* qb = Q + ((size_t)bh * 2048 + q0 + lr) * 64 + lg * 8;
  const bf16x8 qfB0 = *(const bf16x8*)qb;
  const bf16x8 qfB1 = *(const bf16x8*)(qb + 32);

  const bf16* Kbase = Kc + (size_t)bh * 2048 * 64;
  const bf16* Vbase = Vt + (size_t)bh * 64 * 2048;

  const int srow = tid >> 2;
  const int scol = (tid & 3) * 16;
  const int r7x = (srow & 7) * 8;
  const int d0 = srow * 64 + (scol ^ r7x);
  const int d1 = srow * 64 + ((scol + 8) ^ r7x);

  bf16x8 kr0, kr1, vr0, vr1;
  {
    const bf16* kp = Kbase + (size_t)srow * 64 + scol;
    kr0 = *(const bf16x8*)kp;
    kr1 = *(const bf16x8*)(kp + 8);
    const bf16* vp = Vbase + (size_t)srow * 2048 + scol;
    vr0 = *(const bf16x8*)vp;
    vr1 = *(const bf16x8*)(vp + 8);
  }

  f32x4 yacc[4] = {};
  float mrow = -__builtin_inff(), lrow = 0.0f;
  const int kxor = (lr & 7) * 8;

  for (int c = 0; c <= qt; ++c) {
    const int sbase = c * 64;
    __syncthreads();
    *(bf16x8*)&Ks[d0] = kr0;
    *(bf16x8*)&Ks[d1] = kr1;
    *(bf16x8*)&Vs[d0] = vr0;
    *(bf16x8*)&Vs[d1] = vr1;
    __syncthreads();

    {
      const int cn = (c < qt) ? c + 1 : c;
      const int sb = cn * 64;
      const bf16* kp = Kbase + (size_t)(sb + srow) * 64 + scol;
      kr0 = *(const bf16x8*)kp;
      kr1 = *(const bf16x8*)(kp + 8);
      const bf16* vp = Vbase + (size_t)srow * 2048 + sb + scol;
      vr0 = *(const bf16x8*)vp;
      vr1 = *(const bf16x8*)(vp + 8);
    }

    f32x4 st[4];
#pragma unroll
    for (int h = 0; h < 4; ++h) {
      const int rb = (16 * h + lr) * 64;
      const bf16x8 kf0 = *(const bf16x8*)&Ks[rb + ((lg * 8) ^ kxor)];
      const bf16x8 kf1 = *(const bf16x8*)&Ks[rb + ((32 + lg * 8) ^ kxor)];
      f32x4 z = {};
      z = __builtin_amdgcn_mfma_f32_16x16x32_bf16(kf0, qfB0, z, 0, 0, 0);
      z = __builtin_amdgcn_mfma_f32_16x16x32_bf16(kf1, qfB1, z, 0, 0, 0);
      st[h] = z;
    }
    if (c == qt) {  // diagonal chunk: causal mask (Q pre-scaled)
      const int qg = q0 + lr;
#pragma unroll
      for (int h = 0; h < 4; ++h)
#pragma unroll
        for (int j = 0; j < 4; ++j) {
          int sg = sbase + 16 * h + lg * 4 + j;
          if (sg > qg) st[h][j] = -__builtin_inff();
        }
    }
    float vmax = fmaxf(fmaxf(st[0][0], st[0][1]), fmaxf(st[0][2], st[0][3]));
#pragma unroll
    for (int h = 1; h < 4; ++h)
      vmax = fmaxf(vmax, fmaxf(fmaxf(st[h][0], st[h][1]), fmaxf(st[h][2], st[h][3])));
    vmax = fmaxf(vmax, __shfl_xor(vmax, 16));
    vmax = fmaxf(vmax, __shfl_xor(vmax, 32));

    // defer-max (exact, THR=0)
    if (!__all(vmax <= mrow)) {
      const float mnew = fmaxf(mrow, vmax);
      const float cf = EXP2F(mrow - mnew);
      mrow = mnew;
      lrow *= cf;
      float cfj[4];
#pragma unroll
      for (int j = 0; j < 4; ++j) cfj[j] = __shfl(cf, lg * 4 + j);
#pragma unroll
      for (int nf = 0; nf < 4; ++nf)
#pragma unroll
        for (int j = 0; j < 4; ++j) yacc[nf][j] *= cfj[j];
    }

    float rs = 0.0f;
#pragma unroll
    for (int h = 0; h < 4; ++h) {
      float p0 = EXP2F(st[h][0] - mrow);
      float p1 = EXP2F(st[h][1] - mrow);
      float p2 = EXP2F(st[h][2] - mrow);
      float p3 = EXP2F(st[h][3] - mrow);
      rs += (p0 + p1) + (p2 + p3);
      bf16x4 pk = {(bf16)p0, (bf16)p1, (bf16)p2, (bf16)p3};
      *(bf16x4*)&Plds[w][lr][16 * h + lg * 4] = pk;
    }
    rs += __shfl_xor(rs, 16);
    rs += __shfl_xor(rs, 32);
    lrow += rs;

    const bf16x8 pa0 = *(const bf16x8*)&Plds[w][lr][lg * 8];
    const bf16x8 pa1 = *(const bf16x8*)&Plds[w][lr][32 + lg * 8];
#pragma unroll
    for (int nf = 0; nf < 4; ++nf) {
      const int rb = (nf * 16 + lr) * 64;
      const bf16x8 vf0 = *(const bf16x8*)&Vs[rb + ((lg * 8) ^ kxor)];
      const bf16x8 vf1 = *(const bf16x8*)&Vs[rb + ((32 + lg * 8) ^ kxor)];
      yacc[nf] = __builtin_amdgcn_mfma_f32_16x16x32_bf16(pa0, vf0, yacc[nf], 0, 0, 0);
      yacc[nf] = __builtin_amdgcn_mfma_f32_16x16x32_bf16(pa1, vf1, yacc[nf], 0, 0, 0);
    }
  }

  const float rinv = 1.0f / lrow;
  float linv[4];
#pragma unroll
  for (int j = 0; j < 4; ++j) linv[j] = __shfl(rinv, lg * 4 + j);
  const int b = bh >> 4, h = bh & 15;
#pragma unroll
  for (int nf = 0; nf < 4; ++nf)
#pragma unroll
    for (int j = 0; j < 4; ++j) {
      int qg = q0 + lg * 4 + j;
      Y[((size_t)b * 2048 + qg) * 1024 + h * 64 + nf * 16 + lr] = (bf16)(yacc[nf][j] * linv[j]);
    }
}

extern "C" void kernel_launch(void* const* d_in, const int* in_sizes, int n_in,
                              void* d_out, int out_size, void* d_ws, size_t ws_size,
                              hipStream_t stream) {
  const float* x = (const float*)d_in[0];
  const float* ctx = (const float*)d_in[1];
  const float* q_w = (const float*)d_in[2];
  const float* q_b = (const float*)d_in[3];
  const float* k_w = (const float*)d_in[4];
  const float* k_b = (const float*)d_in[5];
  const float* v_w = (const float*)d_in[6];
  const float* v_b = (const float*)d_in[7];
  const float* o_w = (const float*)d_in[8];
  const float* o_b = (const float*)d_in[9];

  char* ws = (char*)d_ws;
  const size_t MB = 1024 * 1024;
  bf16* qwt = (bf16*)(ws + 0);         // 4 transposed weights, 2MB stride
  bf16* Qws = (bf16*)(ws + 8 * MB);    // Q, K, V^T at 8MB stride
  bf16* Kws = (bf16*)(ws + 16 * MB);
  bf16* Vt = (bf16*)(ws + 24 * MB);
  bf16* Yws = (bf16*)(ws + 32 * MB);
  bf16* owt = qwt + 3 * 1048576;

  dim3 tb(32, 8), tg(32, 32, 4);
  transpose_kernel<<<tg, tb, 0, stream>>>(q_w, k_w, v_w, o_w, qwt);

  gemm_qkv_kernel<<<768, 256, 0, stream>>>(x, ctx, qwt, q_b, k_b, v_b, Qws);

  attn_kernel<<<dim3(32, 32), 256, 0, stream>>>(Qws, Kws, Vt, Yws);

  gemm_o_kernel<<<256, 256, 0, stream>>>(Yws, owt, o_b, (float*)d_out);
}